// Round 1
// baseline (105.217 us; speedup 1.0000x reference)
//
#include <hip/hip_runtime.h>
#include <math.h>

typedef short bf16x8 __attribute__((ext_vector_type(8)));
typedef float f32x4 __attribute__((ext_vector_type(4)));

__device__ __forceinline__ short f2bf(float f) {
    union { float f; unsigned int u; } v; v.f = f;
    unsigned int r = v.u + 0x7FFFu + ((v.u >> 16) & 1u);
    return (short)(r >> 16);
}

// out[128][ldo] cols [c0, c0+32) = act[128][1024] @ wgt[N][1024]^T (+bias, +relu)
// Source (act, wgt) switches at column `split` (for the fused gi|gh gates GEMM).
__global__ __launch_bounds__(256) void gemm_k(
    const float* __restrict__ act0, const float* __restrict__ wgt0,
    const float* __restrict__ act1, const float* __restrict__ wgt1,
    int split, const float* __restrict__ bias, int relu,
    float* __restrict__ out, int ldo)
{
    __shared__ short As[128 * 64];   // [row][k] bf16, XOR-swizzled
    __shared__ short Ws[32 * 64];
    const int tid  = threadIdx.x;
    const int lane = tid & 63;
    const int wv   = tid >> 6;
    const int c0   = blockIdx.x * 32;

    const float* act = act0;
    const float* wgt = wgt0;
    int wr0 = c0;
    if (c0 >= split) { act = act1; wgt = wgt1; wr0 = c0 - split; }

    f32x4 acc[2][2] = {};

    for (int kt = 0; kt < 16; ++kt) {
        const int k0 = kt * 64;
        __syncthreads();
        // stage A tile: 128x64 f32 -> bf16, 4 chunks of 8 per thread
        #pragma unroll
        for (int i = 0; i < 4; ++i) {
            int c = tid + 256 * i;          // chunk 0..1023
            int row = c >> 3, kc = c & 7;
            const float* s = act + row * 1024 + k0 + kc * 8;
            f32x4 v0 = *(const f32x4*)s;
            f32x4 v1 = *(const f32x4*)(s + 4);
            bf16x8 bv;
            bv[0]=f2bf(v0[0]); bv[1]=f2bf(v0[1]); bv[2]=f2bf(v0[2]); bv[3]=f2bf(v0[3]);
            bv[4]=f2bf(v1[0]); bv[5]=f2bf(v1[1]); bv[6]=f2bf(v1[2]); bv[7]=f2bf(v1[3]);
            int idx = (row * 64 + kc * 8) ^ ((row & 7) << 3);
            *(bf16x8*)&As[idx] = bv;
        }
        // stage W tile: 32x64, 1 chunk of 8 per thread
        {
            int row = tid >> 3, kc = tid & 7;
            const float* s = wgt + (wr0 + row) * 1024 + k0 + kc * 8;
            f32x4 v0 = *(const f32x4*)s;
            f32x4 v1 = *(const f32x4*)(s + 4);
            bf16x8 bv;
            bv[0]=f2bf(v0[0]); bv[1]=f2bf(v0[1]); bv[2]=f2bf(v0[2]); bv[3]=f2bf(v0[3]);
            bv[4]=f2bf(v1[0]); bv[5]=f2bf(v1[1]); bv[6]=f2bf(v1[2]); bv[7]=f2bf(v1[3]);
            int idx = (row * 64 + kc * 8) ^ ((row & 7) << 3);
            *(bf16x8*)&Ws[idx] = bv;
        }
        __syncthreads();

        #pragma unroll
        for (int kk = 0; kk < 64; kk += 32) {
            const int kl = kk + 8 * (lane >> 4);   // frag: lane holds k = kl..kl+7
            bf16x8 af[2], bw[2];
            #pragma unroll
            for (int t = 0; t < 2; ++t) {
                int ar = wv * 32 + t * 16 + (lane & 15);
                af[t] = *(const bf16x8*)&As[(ar * 64 + kl) ^ ((ar & 7) << 3)];
                int br = t * 16 + (lane & 15);
                bw[t] = *(const bf16x8*)&Ws[(br * 64 + kl) ^ ((br & 7) << 3)];
            }
            #pragma unroll
            for (int rt = 0; rt < 2; ++rt)
                #pragma unroll
                for (int ct = 0; ct < 2; ++ct)
                    acc[rt][ct] = __builtin_amdgcn_mfma_f32_16x16x32_bf16(
                        af[rt], bw[ct], acc[rt][ct], 0, 0, 0);
        }
    }

    // epilogue: D layout col = lane&15, row = (lane>>4)*4 + reg
    #pragma unroll
    for (int rt = 0; rt < 2; ++rt) {
        #pragma unroll
        for (int ct = 0; ct < 2; ++ct) {
            int col = c0 + ct * 16 + (lane & 15);
            float bv = bias ? bias[col] : 0.0f;
            #pragma unroll
            for (int r = 0; r < 4; ++r) {
                int row = wv * 32 + rt * 16 + (lane >> 4) * 4 + r;
                float v = acc[rt][ct][r] + bv;
                if (relu) v = fmaxf(v, 0.0f);
                out[row * ldo + col] = v;
            }
        }
    }
}

// GRU elementwise: g = [gi | gh] raw GEMM outputs [128][6144]
__global__ __launch_bounds__(256) void gru_k(
    const float* __restrict__ g, const float* __restrict__ x,
    const float* __restrict__ h1,
    const float* __restrict__ b_ih, const float* __restrict__ b_hh,
    float* __restrict__ h1p_out, float* __restrict__ res)
{
    int id = blockIdx.x * 256 + threadIdx.x;   // 0..131071
    int m = id >> 10, j = id & 1023;
    const float* gr = g + m * 6144;
    float ir  = gr[j]        + b_ih[j];
    float iz  = gr[1024 + j] + b_ih[1024 + j];
    float in_ = gr[2048 + j] + b_ih[2048 + j];
    float hr  = gr[3072 + j] + b_hh[j];
    float hz  = gr[4096 + j] + b_hh[1024 + j];
    float hn  = gr[5120 + j] + b_hh[2048 + j];
    float r = 1.0f / (1.0f + __expf(-(ir + hr)));
    float z = 1.0f / (1.0f + __expf(-(iz + hz)));
    float n = tanhf(in_ + r * hn);
    float hp = (1.0f - z) * n + z * h1[id];
    h1p_out[id] = hp;
    res[id] = hp + x[id];
}

extern "C" void kernel_launch(void* const* d_in, const int* in_sizes, int n_in,
                              void* d_out, int out_size, void* d_ws, size_t ws_size,
                              hipStream_t stream)
{
    const float* x     = (const float*)d_in[0];
    const float* h1    = (const float*)d_in[1];
    const float* w_ih  = (const float*)d_in[2];
    const float* w_hh  = (const float*)d_in[3];
    const float* b_ih  = (const float*)d_in[4];
    const float* b_hh  = (const float*)d_in[5];
    const float* w_fc1 = (const float*)d_in[6];
    const float* b_fc1 = (const float*)d_in[7];
    const float* w_fc3 = (const float*)d_in[8];
    const float* b_fc3 = (const float*)d_in[9];

    float* out = (float*)d_out;          // [128][256]
    float* h1p = out + 128 * 256;        // [128][1024]

    char* ws = (char*)d_ws;
    float* g     = (float*)ws;                                   // [128][6144]
    float* res   = (float*)(ws + 128 * 6144 * 4);                // [128][1024]
    float* relu1 = (float*)(ws + 128 * 6144 * 4 + 128 * 1024 * 4); // [128][1024]

    // gates: [gi | gh] = [x @ w_ih^T | h1 @ w_hh^T]  (no bias; gru_k adds them)
    gemm_k<<<192, 256, 0, stream>>>(x, w_ih, h1, w_hh, 3072, nullptr, 0, g, 6144);
    // GRU elementwise -> h1' (to d_out) and res = h1' + x (to ws)
    gru_k<<<512, 256, 0, stream>>>(g, x, h1, b_ih, b_hh, h1p, res);
    // relu1 = relu(res @ w_fc1^T + b_fc1)
    gemm_k<<<32, 256, 0, stream>>>(res, w_fc1, res, w_fc1, 1 << 30, b_fc1, 1, relu1, 1024);
    // out = relu1 @ w_fc3^T + b_fc3
    gemm_k<<<8, 256, 0, stream>>>(relu1, w_fc3, relu1, w_fc3, 1 << 30, b_fc3, 0, out, 256);
}

// Round 2
// 39.686 us; speedup vs baseline: 2.6512x; 2.6512x over previous
//
#include <hip/hip_runtime.h>
#include <math.h>

typedef short bf16x8 __attribute__((ext_vector_type(8)));
typedef float f32x4 __attribute__((ext_vector_type(4)));

__device__ __forceinline__ int cvt2(float lo, float hi) {
    int r;
    asm("v_cvt_pk_bf16_f32 %0, %1, %2" : "=v"(r) : "v"(lo), "v"(hi));
    return r;
}

// out[128][ldo] cols [c0, c0+NT) = act[128][1024] @ wgt[N][1024]^T (+bias,+relu)
// Source switches at column `split` (fused gi|gh gates GEMM).
// Pipelined: 2-deep register prefetch -> double-buffered LDS, raw s_barrier
// with lgkm-only wait so global loads stay in flight across barriers.
template<int NT>
__global__ __launch_bounds__(256, 2) void gemm_k(
    const float* __restrict__ act0, const float* __restrict__ wgt0,
    const float* __restrict__ act1, const float* __restrict__ wgt1,
    int split, const float* __restrict__ bias, int relu,
    float* __restrict__ out, int ldo)
{
    constexpr int CT = NT / 16;           // B col-frags per wave
    __shared__ short As0[128 * 64];
    __shared__ short Ws0[NT * 64];
    __shared__ short As1[128 * 64];
    __shared__ short Ws1[NT * 64];

    const int tid  = threadIdx.x;
    const int lane = tid & 63;
    const int wv   = tid >> 6;
    const int c0   = blockIdx.x * NT;

    const float* act = act0;
    const float* wgt = wgt0;
    int wr0 = c0;
    if (c0 >= split) { act = act1; wgt = wgt1; wr0 = c0 - split; }

    // staging geometry: thread covers rows r0+32i (i=0..3) of A, row r0 of W
    const int r0 = tid >> 3, kc = tid & 7;
    const float* aP = act + r0 * 1024 + kc * 8;
    const float* wP = wgt + (wr0 + r0) * 1024 + kc * 8;
    const bool wAct = (tid < NT * 8);

    int saI[4];
    #pragma unroll
    for (int i = 0; i < 4; ++i) {
        int row = r0 + 32 * i;
        saI[i] = (row * 64 + kc * 8) ^ ((row & 7) << 3);
    }
    const int swI = (r0 * 64 + kc * 8) ^ ((r0 & 7) << 3);

    f32x4 A0[8], A1[8], W0[2], W1[2];
    f32x4 acc[2][CT] = {};

#define ISSUE(kt, A, W) do {                                              \
        _Pragma("unroll")                                                 \
        for (int i = 0; i < 4; ++i) {                                     \
            A[2*i]   = *(const f32x4*)(aP + (kt) * 64 + i * 32768);       \
            A[2*i+1] = *(const f32x4*)(aP + (kt) * 64 + i * 32768 + 4);   \
        }                                                                 \
        if (wAct) {                                                       \
            W[0] = *(const f32x4*)(wP + (kt) * 64);                       \
            W[1] = *(const f32x4*)(wP + (kt) * 64 + 4);                   \
        }                                                                 \
    } while (0)

#define STAGE(A, W, AS, WS) do {                                          \
        _Pragma("unroll")                                                 \
        for (int i = 0; i < 4; ++i) {                                     \
            int4 pk;                                                      \
            pk.x = cvt2(A[2*i][0],   A[2*i][1]);                          \
            pk.y = cvt2(A[2*i][2],   A[2*i][3]);                          \
            pk.z = cvt2(A[2*i+1][0], A[2*i+1][1]);                        \
            pk.w = cvt2(A[2*i+1][2], A[2*i+1][3]);                        \
            *(int4*)&AS[saI[i]] = pk;                                     \
        }                                                                 \
        if (wAct) {                                                       \
            int4 qk;                                                      \
            qk.x = cvt2(W[0][0], W[0][1]);                                \
            qk.y = cvt2(W[0][2], W[0][3]);                                \
            qk.z = cvt2(W[1][0], W[1][1]);                                \
            qk.w = cvt2(W[1][2], W[1][3]);                                \
            *(int4*)&WS[swI] = qk;                                        \
        }                                                                 \
    } while (0)

#define COMPUTE(AS, WS) do {                                              \
        _Pragma("unroll")                                                 \
        for (int kk = 0; kk < 64; kk += 32) {                             \
            const int kw = kk + 8 * (lane >> 4);                          \
            bf16x8 af[2], bw[CT];                                         \
            _Pragma("unroll")                                             \
            for (int t = 0; t < 2; ++t) {                                 \
                int ar = wv * 32 + t * 16 + (lane & 15);                  \
                af[t] = *(const bf16x8*)&AS[(ar * 64 + kw) ^ ((ar & 7) << 3)]; \
            }                                                             \
            _Pragma("unroll")                                             \
            for (int ct = 0; ct < CT; ++ct) {                             \
                int br = ct * 16 + (lane & 15);                           \
                bw[ct] = *(const bf16x8*)&WS[(br * 64 + kw) ^ ((br & 7) << 3)]; \
            }                                                             \
            _Pragma("unroll")                                             \
            for (int rt = 0; rt < 2; ++rt)                                \
                _Pragma("unroll")                                         \
                for (int ct = 0; ct < CT; ++ct)                           \
                    acc[rt][ct] = __builtin_amdgcn_mfma_f32_16x16x32_bf16(\
                        af[rt], bw[ct], acc[rt][ct], 0, 0, 0);            \
        }                                                                 \
    } while (0)

#define BAR() do {                                                        \
        asm volatile("s_waitcnt lgkmcnt(0)" ::: "memory");                \
        __builtin_amdgcn_s_barrier();                                     \
        __builtin_amdgcn_sched_barrier(0);                                \
    } while (0)

    ISSUE(0, A0, W0);
    ISSUE(1, A1, W1);

    #pragma unroll 1
    for (int kt2 = 0; kt2 < 8; ++kt2) {
        const int kt = 2 * kt2;
        STAGE(A0, W0, As0, Ws0);
        if (kt + 2 < 16) ISSUE(kt + 2, A0, W0);
        BAR();
        COMPUTE(As0, Ws0);

        STAGE(A1, W1, As1, Ws1);
        if (kt + 3 < 16) ISSUE(kt + 3, A1, W1);
        BAR();
        COMPUTE(As1, Ws1);
    }

#undef ISSUE
#undef STAGE
#undef COMPUTE
#undef BAR

    // epilogue: D layout col = lane&15, row = (lane>>4)*4 + reg
    #pragma unroll
    for (int rt = 0; rt < 2; ++rt) {
        #pragma unroll
        for (int ct = 0; ct < CT; ++ct) {
            int col = c0 + ct * 16 + (lane & 15);
            float bv = bias ? bias[col] : 0.0f;
            #pragma unroll
            for (int r = 0; r < 4; ++r) {
                int row = wv * 32 + rt * 16 + (lane >> 4) * 4 + r;
                float v = acc[rt][ct][r] + bv;
                if (relu) v = fmaxf(v, 0.0f);
                out[row * ldo + col] = v;
            }
        }
    }
}

// GRU elementwise: g = [gi | gh] raw GEMM outputs [128][6144]
__global__ __launch_bounds__(256) void gru_k(
    const float* __restrict__ g, const float* __restrict__ x,
    const float* __restrict__ h1,
    const float* __restrict__ b_ih, const float* __restrict__ b_hh,
    float* __restrict__ h1p_out, float* __restrict__ res)
{
    int id = blockIdx.x * 256 + threadIdx.x;   // 0..131071
    int m = id >> 10, j = id & 1023;
    const float* gr = g + m * 6144;
    float ir  = gr[j]        + b_ih[j];
    float iz  = gr[1024 + j] + b_ih[1024 + j];
    float in_ = gr[2048 + j] + b_ih[2048 + j];
    float hr  = gr[3072 + j] + b_hh[j];
    float hz  = gr[4096 + j] + b_hh[1024 + j];
    float hn  = gr[5120 + j] + b_hh[2048 + j];
    float r = 1.0f / (1.0f + __expf(-(ir + hr)));
    float z = 1.0f / (1.0f + __expf(-(iz + hz)));
    float n = tanhf(in_ + r * hn);
    float hp = (1.0f - z) * n + z * h1[id];
    h1p_out[id] = hp;
    res[id] = hp + x[id];
}

extern "C" void kernel_launch(void* const* d_in, const int* in_sizes, int n_in,
                              void* d_out, int out_size, void* d_ws, size_t ws_size,
                              hipStream_t stream)
{
    const float* x     = (const float*)d_in[0];
    const float* h1    = (const float*)d_in[1];
    const float* w_ih  = (const float*)d_in[2];
    const float* w_hh  = (const float*)d_in[3];
    const float* b_ih  = (const float*)d_in[4];
    const float* b_hh  = (const float*)d_in[5];
    const float* w_fc1 = (const float*)d_in[6];
    const float* b_fc1 = (const float*)d_in[7];
    const float* w_fc3 = (const float*)d_in[8];
    const float* b_fc3 = (const float*)d_in[9];

    float* out = (float*)d_out;          // [128][256]
    float* h1p = out + 128 * 256;        // [128][1024]

    char* ws = (char*)d_ws;
    float* g     = (float*)ws;                                     // [128][6144]
    float* res   = (float*)(ws + 128 * 6144 * 4);                  // [128][1024]
    float* relu1 = (float*)(ws + 128 * 6144 * 4 + 128 * 1024 * 4); // [128][1024]

    // gates: [gi | gh] = [x @ w_ih^T | h1 @ w_hh^T]  (no bias; gru_k adds them)
    gemm_k<32><<<192, 256, 0, stream>>>(x, w_ih, h1, w_hh, 3072, nullptr, 0, g, 6144);
    // GRU elementwise -> h1' (to d_out) and res = h1' + x (to ws)
    gru_k<<<512, 256, 0, stream>>>(g, x, h1, b_ih, b_hh, h1p, res);
    // relu1 = relu(res @ w_fc1^T + b_fc1)
    gemm_k<16><<<64, 256, 0, stream>>>(res, w_fc1, res, w_fc1, 1 << 30, b_fc1, 1, relu1, 1024);
    // out = relu1 @ w_fc3^T + b_fc3
    gemm_k<16><<<16, 256, 0, stream>>>(relu1, w_fc3, relu1, w_fc3, 1 << 30, b_fc3, 0, out, 256);
}

// Round 3
// 31.752 us; speedup vs baseline: 3.3137x; 1.2499x over previous
//
#include <hip/hip_runtime.h>
#include <math.h>

typedef short bf16x8 __attribute__((ext_vector_type(8)));
typedef float f32x4 __attribute__((ext_vector_type(4)));

__device__ __forceinline__ int cvt2(float lo, float hi) {
    int r;
    asm("v_cvt_pk_bf16_f32 %0, %1, %2" : "=v"(r) : "v"(lo), "v"(hi));
    return r;
}

// out rows [rg*64, rg*64+64) cols [c0, c0+NT) (+)= act[128][1024] @ wgt[N][1024]^T
// K-range [ks*nkt*64, ...) per block; ATOMIC: atomicAdd epilogue (split-K).
// RELUA: apply relu to A during bf16 staging (fc3 consuming raw fc1 pre-act).
// 4-deep register prefetch -> double-buffered LDS; lgkm-only barriers so
// global loads stay in flight across barriers (counted vmcnt by compiler).
template<int NT, bool ATOMIC, bool RELUA>
__global__ __launch_bounds__(256, 2) void gemm_k(
    const float* __restrict__ act0, const float* __restrict__ wgt0,
    const float* __restrict__ act1, const float* __restrict__ wgt1,
    int split, const float* __restrict__ bias,
    float* __restrict__ out, int ldo, int nkt, int ksbits)
{
    constexpr int CT = NT / 16;
    __shared__ short As[2][64 * 64];
    __shared__ short Ws[2][NT * 64];

    const int tid  = threadIdx.x;
    const int lane = tid & 63;
    const int wv   = tid >> 6;

    const int ks   = blockIdx.x & ((1 << ksbits) - 1);
    const int rest = blockIdx.x >> ksbits;
    const int rg   = rest & 1;
    const int tile = rest >> 1;
    const int c0   = tile * NT;
    const int row0 = rg * 64;
    const int kt0  = ks * nkt;

    const float* act = act0;
    const float* wgt = wgt0;
    int wr0 = c0;
    if (c0 >= split) { act = act1; wgt = wgt1; wr0 = c0 - split; }

    // staging geometry: thread covers A rows r0, r0+32 (kc chunk), W row r0
    const int r0 = tid >> 3, kc = tid & 7;
    const float* aP = act + (row0 + r0) * 1024 + kt0 * 64 + kc * 8;
    const float* wP = wgt + (wr0 + r0) * 1024 + kt0 * 64 + kc * 8;
    const bool wAct = (tid < NT * 8);

    const int saI0 = (r0 * 64 + kc * 8) ^ ((r0 & 7) << 3);
    const int saI1 = ((r0 + 32) * 64 + kc * 8) ^ ((r0 & 7) << 3);

    f32x4 A[4][4], W[4][2];
    f32x4 acc[CT] = {};

#define ISSUE(kt, s) do {                                                 \
        A[s][0] = *(const f32x4*)(aP + (kt) * 64);                        \
        A[s][1] = *(const f32x4*)(aP + (kt) * 64 + 4);                    \
        A[s][2] = *(const f32x4*)(aP + (kt) * 64 + 32768);                \
        A[s][3] = *(const f32x4*)(aP + (kt) * 64 + 32772);                \
        if (wAct) {                                                       \
            W[s][0] = *(const f32x4*)(wP + (kt) * 64);                    \
            W[s][1] = *(const f32x4*)(wP + (kt) * 64 + 4);                \
        }                                                                 \
    } while (0)

#define RL(x) (RELUA ? fmaxf((x), 0.0f) : (x))

#define STAGE(s, b) do {                                                  \
        int4 p0, p1;                                                      \
        p0.x = cvt2(RL(A[s][0][0]), RL(A[s][0][1]));                      \
        p0.y = cvt2(RL(A[s][0][2]), RL(A[s][0][3]));                      \
        p0.z = cvt2(RL(A[s][1][0]), RL(A[s][1][1]));                      \
        p0.w = cvt2(RL(A[s][1][2]), RL(A[s][1][3]));                      \
        p1.x = cvt2(RL(A[s][2][0]), RL(A[s][2][1]));                      \
        p1.y = cvt2(RL(A[s][2][2]), RL(A[s][2][3]));                      \
        p1.z = cvt2(RL(A[s][3][0]), RL(A[s][3][1]));                      \
        p1.w = cvt2(RL(A[s][3][2]), RL(A[s][3][3]));                      \
        *(int4*)&As[b][saI0] = p0;                                        \
        *(int4*)&As[b][saI1] = p1;                                        \
        if (wAct) {                                                       \
            int4 q;                                                       \
            q.x = cvt2(W[s][0][0], W[s][0][1]);                           \
            q.y = cvt2(W[s][0][2], W[s][0][3]);                           \
            q.z = cvt2(W[s][1][0], W[s][1][1]);                           \
            q.w = cvt2(W[s][1][2], W[s][1][3]);                           \
            *(int4*)&Ws[b][saI0] = q;                                     \
        }                                                                 \
    } while (0)

#define COMPUTE(b) do {                                                   \
        _Pragma("unroll")                                                 \
        for (int kk = 0; kk < 64; kk += 32) {                             \
            const int kw = kk + 8 * (lane >> 4);                          \
            const int ar = wv * 16 + (lane & 15);                         \
            bf16x8 af = *(const bf16x8*)&As[b][(ar * 64 + kw) ^ ((ar & 7) << 3)]; \
            bf16x8 bw[CT];                                                \
            _Pragma("unroll")                                             \
            for (int ct = 0; ct < CT; ++ct) {                             \
                int br = ct * 16 + (lane & 15);                           \
                bw[ct] = *(const bf16x8*)&Ws[b][(br * 64 + kw) ^ ((br & 7) << 3)]; \
            }                                                             \
            _Pragma("unroll")                                             \
            for (int ct = 0; ct < CT; ++ct)                               \
                acc[ct] = __builtin_amdgcn_mfma_f32_16x16x32_bf16(        \
                    af, bw[ct], acc[ct], 0, 0, 0);                        \
        }                                                                 \
    } while (0)

#define BAR() do {                                                        \
        asm volatile("s_waitcnt lgkmcnt(0)" ::: "memory");                \
        __builtin_amdgcn_s_barrier();                                     \
        __builtin_amdgcn_sched_barrier(0);                                \
    } while (0)

    ISSUE(0, 0); ISSUE(1, 1); ISSUE(2, 2); ISSUE(3, 3);

    #pragma unroll 1
    for (int g = 0; g < nkt / 4; ++g) {
        const int kt = 4 * g;
        STAGE(0, 0); if (kt + 4 < nkt) ISSUE(kt + 4, 0); BAR(); COMPUTE(0);
        STAGE(1, 1); if (kt + 5 < nkt) ISSUE(kt + 5, 1); BAR(); COMPUTE(1);
        STAGE(2, 0); if (kt + 6 < nkt) ISSUE(kt + 6, 2); BAR(); COMPUTE(0);
        STAGE(3, 1); if (kt + 7 < nkt) ISSUE(kt + 7, 3); BAR(); COMPUTE(1);
    }

#undef ISSUE
#undef RL
#undef STAGE
#undef COMPUTE
#undef BAR

    // epilogue: D layout col = lane&15, row = (lane>>4)*4 + reg
    #pragma unroll
    for (int ct = 0; ct < CT; ++ct) {
        int col = c0 + ct * 16 + (lane & 15);
        float bv = (bias && ks == 0) ? bias[col] : 0.0f;
        #pragma unroll
        for (int r = 0; r < 4; ++r) {
            int row = row0 + wv * 16 + (lane >> 4) * 4 + r;
            float v = acc[ct][r] + bv;
            if (ATOMIC) unsafeAtomicAdd(&out[row * ldo + col], v);
            else        out[row * ldo + col] = v;
        }
    }
}

// GRU elementwise over [128][1024]; also zero-inits the two atomic targets
// (fc1 pre-act buffer and the fc3 output region) before their split-K GEMMs.
__global__ __launch_bounds__(256) void gru_k(
    const float* __restrict__ g, const float* __restrict__ x,
    const float* __restrict__ h1,
    const float* __restrict__ b_ih, const float* __restrict__ b_hh,
    float* __restrict__ h1p_out, float* __restrict__ res,
    float* __restrict__ zero_f1p, float* __restrict__ zero_out)
{
    int id = blockIdx.x * 256 + threadIdx.x;   // 0..131071
    zero_f1p[id] = 0.0f;
    if (id < 128 * 256) zero_out[id] = 0.0f;
    int m = id >> 10, j = id & 1023;
    const float* gr = g + m * 6144;
    float ir  = gr[j]        + b_ih[j];
    float iz  = gr[1024 + j] + b_ih[1024 + j];
    float in_ = gr[2048 + j] + b_ih[2048 + j];
    float hr  = gr[3072 + j] + b_hh[j];
    float hz  = gr[4096 + j] + b_hh[1024 + j];
    float hn  = gr[5120 + j] + b_hh[2048 + j];
    float r = 1.0f / (1.0f + __expf(-(ir + hr)));
    float z = 1.0f / (1.0f + __expf(-(iz + hz)));
    float n = tanhf(in_ + r * hn);
    float hp = (1.0f - z) * n + z * h1[id];
    h1p_out[id] = hp;
    res[id] = hp + x[id];
}

extern "C" void kernel_launch(void* const* d_in, const int* in_sizes, int n_in,
                              void* d_out, int out_size, void* d_ws, size_t ws_size,
                              hipStream_t stream)
{
    const float* x     = (const float*)d_in[0];
    const float* h1    = (const float*)d_in[1];
    const float* w_ih  = (const float*)d_in[2];
    const float* w_hh  = (const float*)d_in[3];
    const float* b_ih  = (const float*)d_in[4];
    const float* b_hh  = (const float*)d_in[5];
    const float* w_fc1 = (const float*)d_in[6];
    const float* b_fc1 = (const float*)d_in[7];
    const float* w_fc3 = (const float*)d_in[8];
    const float* b_fc3 = (const float*)d_in[9];

    float* out = (float*)d_out;          // [128][256]
    float* h1p = out + 128 * 256;        // [128][1024]

    float* ws  = (float*)d_ws;
    float* g   = ws;                     // [128][6144] raw gates
    float* res = ws + 128 * 6144;        // [128][1024] h1' + x
    float* f1p = res + 128 * 1024;       // [128][1024] fc1 pre-activation

    // gates: [gi | gh] = [x @ w_ih^T | h1 @ w_hh^T]  (biases added in gru_k)
    // 192 col-tiles x 2 row-groups = 384 blocks, 16 K-steps
    gemm_k<32, false, false><<<384, 256, 0, stream>>>(
        x, w_ih, h1, w_hh, 3072, nullptr, g, 6144, 16, 0);
    // GRU elementwise -> h1' (d_out) and res (ws); zero f1p and out region
    gru_k<<<512, 256, 0, stream>>>(g, x, h1, b_ih, b_hh, h1p, res, f1p, out);
    // f1p += res @ w_fc1^T + b_fc1   (64 tiles x 2 rg x 2 ksplit = 256 blocks)
    gemm_k<16, true, false><<<256, 256, 0, stream>>>(
        res, w_fc1, res, w_fc1, 1 << 30, b_fc1, f1p, 1024, 8, 1);
    // out += relu(f1p) @ w_fc3^T + b_fc3  (16 x 2 x 2 = 64 blocks)
    gemm_k<16, true, true><<<64, 256, 0, stream>>>(
        f1p, w_fc3, f1p, w_fc3, 1 << 30, b_fc3, out, 256, 8, 1);
}

// Round 4
// 30.204 us; speedup vs baseline: 3.4835x; 1.0513x over previous
//
#include <hip/hip_runtime.h>
#include <math.h>

typedef short bf16x8 __attribute__((ext_vector_type(8)));
typedef float f32x4 __attribute__((ext_vector_type(4)));

__device__ __forceinline__ int cvt2(float lo, float hi) {
    int r;
    asm("v_cvt_pk_bf16_f32 %0, %1, %2" : "=v"(r) : "v"(lo), "v"(hi));
    return r;
}

#define BAR() do {                                                        \
        asm volatile("s_waitcnt lgkmcnt(0)" ::: "memory");                \
        __builtin_amdgcn_s_barrier();                                     \
        __builtin_amdgcn_sched_barrier(0);                                \
    } while (0)

// ---------------------------------------------------------------------------
// Fused gates GEMM + GRU elementwise.
// grid 128; block computes ALL 6 gate tiles (i_r,i_z,i_n,h_r,h_z,h_n) for a
// 64-row x 16-col patch, then does the GRU math in-register and writes
// h1' and res = h1' + x. blockIdx remapped so the two row-groups of a tile
// land on the same XCD (W-slice L2 reuse).
__global__ __launch_bounds__(256, 2) void gates_k(
    const float* __restrict__ x, const float* __restrict__ h1,
    const float* __restrict__ w_ih, const float* __restrict__ w_hh,
    const float* __restrict__ b_ih, const float* __restrict__ b_hh,
    float* __restrict__ h1p, float* __restrict__ res,
    float* __restrict__ zf1p, float* __restrict__ zout)
{
    __shared__ short As[2][128 * 64];   // meta-rows 0..63 = x, 64..127 = h1
    __shared__ short Ws[2][96 * 64];    // meta-row g*16+jr, gates 0..5
    const int tid  = threadIdx.x;
    const int lane = tid & 63;
    const int wv   = tid >> 6;

    // zero split-K atomic targets (fc1 pre-act, fc3 output region)
    {
        int id = blockIdx.x * 256 + tid;           // 0..32767
        f32x4 z = {};
        *(f32x4*)(zf1p + id * 4) = z;
        zout[id] = 0.0f;
    }

    // XCD-pairing remap: both rg of a tile share b%8 (same XCD assumption)
    const int b    = blockIdx.x;
    const int tile = (b & 7) * 8 + ((b >> 3) >> 1);   // 0..63
    const int rg   = (b >> 3) & 1;
    const int c0   = tile * 16;
    const int row0 = rg * 64;

    const int r0 = tid >> 3, kc = tid & 7;

    // A staging: 4 meta-rows per thread (x rows, then h1 rows)
    const float* aP[4];
    int saI[4];
    #pragma unroll
    for (int i = 0; i < 4; ++i) {
        int ma = r0 + 32 * i;                         // 0..127
        const float* src = (i < 2) ? x : h1;
        aP[i] = src + (row0 + (ma & 63)) * 1024 + kc * 8;
        saI[i] = (ma * 64 + kc * 8) ^ ((ma & 7) << 3);
    }
    // W staging: 3 meta-rows per thread
    const float* wP[3];
    int swI[3];
    #pragma unroll
    for (int i = 0; i < 3; ++i) {
        int mw = r0 + 32 * i;                         // 0..95
        int g = mw >> 4;                              // gate 0..5
        const float* src = (g < 3) ? w_ih : w_hh;
        wP[i] = src + ((g % 3) * 1024 + c0 + (mw & 15)) * 1024 + kc * 8;
        swI[i] = (mw * 64 + kc * 8) ^ ((mw & 7) << 3);
    }

    f32x4 A[2][4][2], W[2][3][2];
    f32x4 acc[6] = {};

#define G_ISSUE(kt, s) do {                                               \
        _Pragma("unroll")                                                 \
        for (int i = 0; i < 4; ++i) {                                     \
            A[s][i][0] = *(const f32x4*)(aP[i] + (kt) * 64);              \
            A[s][i][1] = *(const f32x4*)(aP[i] + (kt) * 64 + 4);          \
        }                                                                 \
        _Pragma("unroll")                                                 \
        for (int i = 0; i < 3; ++i) {                                     \
            W[s][i][0] = *(const f32x4*)(wP[i] + (kt) * 64);              \
            W[s][i][1] = *(const f32x4*)(wP[i] + (kt) * 64 + 4);          \
        }                                                                 \
    } while (0)

#define G_STAGE(s, bb) do {                                               \
        _Pragma("unroll")                                                 \
        for (int i = 0; i < 4; ++i) {                                     \
            int4 p;                                                       \
            p.x = cvt2(A[s][i][0][0], A[s][i][0][1]);                     \
            p.y = cvt2(A[s][i][0][2], A[s][i][0][3]);                     \
            p.z = cvt2(A[s][i][1][0], A[s][i][1][1]);                     \
            p.w = cvt2(A[s][i][1][2], A[s][i][1][3]);                     \
            *(int4*)&As[bb][saI[i]] = p;                                  \
        }                                                                 \
        _Pragma("unroll")                                                 \
        for (int i = 0; i < 3; ++i) {                                     \
            int4 q;                                                       \
            q.x = cvt2(W[s][i][0][0], W[s][i][0][1]);                     \
            q.y = cvt2(W[s][i][0][2], W[s][i][0][3]);                     \
            q.z = cvt2(W[s][i][1][0], W[s][i][1][1]);                     \
            q.w = cvt2(W[s][i][1][2], W[s][i][1][3]);                     \
            *(int4*)&Ws[bb][swI[i]] = q;                                  \
        }                                                                 \
    } while (0)

#define G_COMPUTE(bb) do {                                                \
        _Pragma("unroll")                                                 \
        for (int kk = 0; kk < 64; kk += 32) {                             \
            const int kw = kk + 8 * (lane >> 4);                          \
            const int ar = wv * 16 + (lane & 15);                         \
            bf16x8 afx = *(const bf16x8*)&As[bb][(ar * 64 + kw) ^ ((ar & 7) << 3)]; \
            bf16x8 afh = *(const bf16x8*)&As[bb][((ar + 64) * 64 + kw) ^ ((ar & 7) << 3)]; \
            _Pragma("unroll")                                             \
            for (int g = 0; g < 6; ++g) {                                 \
                int br = g * 16 + (lane & 15);                            \
                bf16x8 bw = *(const bf16x8*)&Ws[bb][(br * 64 + kw) ^ ((br & 7) << 3)]; \
                acc[g] = __builtin_amdgcn_mfma_f32_16x16x32_bf16(         \
                    (g < 3) ? afx : afh, bw, acc[g], 0, 0, 0);            \
            }                                                             \
        }                                                                 \
    } while (0)

    G_ISSUE(0, 0); G_ISSUE(1, 1);

    #pragma unroll 1
    for (int kt2 = 0; kt2 < 8; ++kt2) {
        const int kt = 2 * kt2;
        G_STAGE(0, 0); if (kt + 2 < 16) G_ISSUE(kt + 2, 0); BAR(); G_COMPUTE(0);
        G_STAGE(1, 1); if (kt + 3 < 16) G_ISSUE(kt + 3, 1); BAR(); G_COMPUTE(1);
    }

#undef G_ISSUE
#undef G_STAGE
#undef G_COMPUTE

    // ---- GRU epilogue (in-register) ----
    const int j = c0 + (lane & 15);
    const float bir = b_ih[j], biz = b_ih[1024 + j], bin = b_ih[2048 + j];
    const float bhr = b_hh[j], bhz = b_hh[1024 + j], bhn = b_hh[2048 + j];
    const int rbase = row0 + wv * 16 + (lane >> 4) * 4;
    #pragma unroll
    for (int r = 0; r < 4; ++r) {
        const int row = rbase + r;
        float ir  = acc[0][r] + bir, iz = acc[1][r] + biz, inn = acc[2][r] + bin;
        float hr  = acc[3][r] + bhr, hz = acc[4][r] + bhz, hn  = acc[5][r] + bhn;
        float rr = 1.0f / (1.0f + __expf(-(ir + hr)));
        float zz = 1.0f / (1.0f + __expf(-(iz + hz)));
        float nn = tanhf(inn + rr * hn);
        float h1v = h1[row * 1024 + j];
        float hp  = (1.0f - zz) * nn + zz * h1v;
        h1p[row * 1024 + j] = hp;
        res[row * 1024 + j] = hp + x[row * 1024 + j];
    }
}

// ---------------------------------------------------------------------------
// Generic tiled GEMM (fc1 / fc3): out rows [rg*64,+64) cols [c0,+NT)
// (+)= act[128][1024] @ wgt[N][1024]^T ; split-K via ksbits + atomics.
template<int NT, bool ATOMIC, bool RELUA>
__global__ __launch_bounds__(256, 2) void gemm_k(
    const float* __restrict__ act, const float* __restrict__ wgt,
    const float* __restrict__ bias,
    float* __restrict__ out, int ldo, int nkt, int ksbits)
{
    constexpr int CT = NT / 16;
    __shared__ short As[2][64 * 64];
    __shared__ short Ws[2][NT * 64];

    const int tid  = threadIdx.x;
    const int lane = tid & 63;
    const int wv   = tid >> 6;

    const int ks   = blockIdx.x & ((1 << ksbits) - 1);
    const int rest = blockIdx.x >> ksbits;
    const int rg   = rest & 1;
    const int tile = rest >> 1;
    const int c0   = tile * NT;
    const int row0 = rg * 64;
    const int kt0  = ks * nkt;

    const int r0 = tid >> 3, kc = tid & 7;
    const float* aP = act + (row0 + r0) * 1024 + kt0 * 64 + kc * 8;
    const float* wP = wgt + (c0 + r0) * 1024 + kt0 * 64 + kc * 8;
    const bool wAct = (tid < NT * 8);

    const int saI0 = (r0 * 64 + kc * 8) ^ ((r0 & 7) << 3);
    const int saI1 = ((r0 + 32) * 64 + kc * 8) ^ ((r0 & 7) << 3);

    f32x4 A[4][4], W[4][2];
    f32x4 acc[CT] = {};

#define ISSUE(kt, s) do {                                                 \
        A[s][0] = *(const f32x4*)(aP + (kt) * 64);                        \
        A[s][1] = *(const f32x4*)(aP + (kt) * 64 + 4);                    \
        A[s][2] = *(const f32x4*)(aP + (kt) * 64 + 32768);                \
        A[s][3] = *(const f32x4*)(aP + (kt) * 64 + 32772);                \
        if (wAct) {                                                       \
            W[s][0] = *(const f32x4*)(wP + (kt) * 64);                    \
            W[s][1] = *(const f32x4*)(wP + (kt) * 64 + 4);                \
        }                                                                 \
    } while (0)

#define RL(v) (RELUA ? fmaxf((v), 0.0f) : (v))

#define STAGE(s, b) do {                                                  \
        int4 p0, p1;                                                      \
        p0.x = cvt2(RL(A[s][0][0]), RL(A[s][0][1]));                      \
        p0.y = cvt2(RL(A[s][0][2]), RL(A[s][0][3]));                      \
        p0.z = cvt2(RL(A[s][1][0]), RL(A[s][1][1]));                      \
        p0.w = cvt2(RL(A[s][1][2]), RL(A[s][1][3]));                      \
        p1.x = cvt2(RL(A[s][2][0]), RL(A[s][2][1]));                      \
        p1.y = cvt2(RL(A[s][2][2]), RL(A[s][2][3]));                      \
        p1.z = cvt2(RL(A[s][3][0]), RL(A[s][3][1]));                      \
        p1.w = cvt2(RL(A[s][3][2]), RL(A[s][3][3]));                      \
        *(int4*)&As[b][saI0] = p0;                                        \
        *(int4*)&As[b][saI1] = p1;                                        \
        if (wAct) {                                                       \
            int4 q;                                                       \
            q.x = cvt2(W[s][0][0], W[s][0][1]);                           \
            q.y = cvt2(W[s][0][2], W[s][0][3]);                           \
            q.z = cvt2(W[s][1][0], W[s][1][1]);                           \
            q.w = cvt2(W[s][1][2], W[s][1][3]);                           \
            *(int4*)&Ws[b][saI0] = q;                                     \
        }                                                                 \
    } while (0)

#define COMPUTE(b) do {                                                   \
        _Pragma("unroll")                                                 \
        for (int kk = 0; kk < 64; kk += 32) {                             \
            const int kw = kk + 8 * (lane >> 4);                          \
            const int ar = wv * 16 + (lane & 15);                         \
            bf16x8 af = *(const bf16x8*)&As[b][(ar * 64 + kw) ^ ((ar & 7) << 3)]; \
            bf16x8 bw[CT];                                                \
            _Pragma("unroll")                                             \
            for (int ct = 0; ct < CT; ++ct) {                             \
                int br = ct * 16 + (lane & 15);                           \
                bw[ct] = *(const bf16x8*)&Ws[b][(br * 64 + kw) ^ ((br & 7) << 3)]; \
            }                                                             \
            _Pragma("unroll")                                             \
            for (int ct = 0; ct < CT; ++ct)                               \
                acc[ct] = __builtin_amdgcn_mfma_f32_16x16x32_bf16(        \
                    af, bw[ct], acc[ct], 0, 0, 0);                        \
        }                                                                 \
    } while (0)

    ISSUE(0, 0); ISSUE(1, 1); ISSUE(2, 2); ISSUE(3, 3);

    #pragma unroll 1
    for (int g = 0; g < nkt / 4; ++g) {
        const int kt = 4 * g;
        STAGE(0, 0); if (kt + 4 < nkt) ISSUE(kt + 4, 0); BAR(); COMPUTE(0);
        STAGE(1, 1); if (kt + 5 < nkt) ISSUE(kt + 5, 1); BAR(); COMPUTE(1);
        STAGE(2, 0); if (kt + 6 < nkt) ISSUE(kt + 6, 2); BAR(); COMPUTE(0);
        STAGE(3, 1); if (kt + 7 < nkt) ISSUE(kt + 7, 3); BAR(); COMPUTE(1);
    }

#undef ISSUE
#undef RL
#undef STAGE
#undef COMPUTE

    #pragma unroll
    for (int ct = 0; ct < CT; ++ct) {
        int col = c0 + ct * 16 + (lane & 15);
        float bv = (bias && ks == 0) ? bias[col] : 0.0f;
        #pragma unroll
        for (int r = 0; r < 4; ++r) {
            int row = row0 + wv * 16 + (lane >> 4) * 4 + r;
            float v = acc[ct][r] + bv;
            if (ATOMIC) unsafeAtomicAdd(&out[row * ldo + col], v);
            else        out[row * ldo + col] = v;
        }
    }
}

extern "C" void kernel_launch(void* const* d_in, const int* in_sizes, int n_in,
                              void* d_out, int out_size, void* d_ws, size_t ws_size,
                              hipStream_t stream)
{
    const float* x     = (const float*)d_in[0];
    const float* h1    = (const float*)d_in[1];
    const float* w_ih  = (const float*)d_in[2];
    const float* w_hh  = (const float*)d_in[3];
    const float* b_ih  = (const float*)d_in[4];
    const float* b_hh  = (const float*)d_in[5];
    const float* w_fc1 = (const float*)d_in[6];
    const float* b_fc1 = (const float*)d_in[7];
    const float* w_fc3 = (const float*)d_in[8];
    const float* b_fc3 = (const float*)d_in[9];

    float* out = (float*)d_out;          // [128][256]
    float* h1p = out + 128 * 256;        // [128][1024]

    float* ws  = (float*)d_ws;
    float* res = ws;                     // [128][1024] h1' + x
    float* f1p = ws + 128 * 1024;        // [128][1024] fc1 pre-activation

    // fused gates GEMM + GRU -> h1p (d_out) and res; zeroes f1p and out
    gates_k<<<128, 256, 0, stream>>>(x, h1, w_ih, w_hh, b_ih, b_hh,
                                     h1p, res, f1p, out);
    // f1p += res @ w_fc1^T + b_fc1   (64 tiles x 2 rg x 2 ksplit = 256 blocks)
    gemm_k<16, true, false><<<256, 256, 0, stream>>>(
        res, w_fc1, b_fc1, f1p, 1024, 8, 1);
    // out += relu(f1p) @ w_fc3^T + b_fc3  (16 x 2 x 2 = 64 blocks)
    gemm_k<16, true, true><<<64, 256, 0, stream>>>(
        f1p, w_fc3, b_fc3, out, 256, 8, 1);
}